// Round 4
// baseline (870.385 us; speedup 1.0000x reference)
//
#include <hip/hip_runtime.h>

// Problem constants: B,S,NODE,DEP,R,L,E = 32,1024,256,64,50,16,128
constexpr int B_ = 32;
constexpr int S_ = 1024;
constexpr int NODE_ = 256;
constexpr int DEP_ = 64;
constexpr int R_ = 50;
constexpr int L_ = 16;
constexpr int E_ = 128;
constexpr int FEAT_ = NODE_ + DEP_;     // 320
constexpr int NEDGE_ = B_ * E_;         // 4096 edges per layer
constexpr int BS_ = B_ * S_;            // 32768 rows
constexpr int CH_ = 16;                 // edges per relation-chunk (chain)
constexpr int NCH_ = 320;               // sum ceil(n_r/16) <= 306
constexpr int PREB_ = 512;              // worker blocks in k_pre
constexpr int GCH_ = 64;                // edges per GLOBAL relation-chunk (k_ctx2)
constexpr int NGC_ = 1088;              // >= 50 + 65536/64 = 1074

// ---------------------------------------------------------------------------
// Key algebra: msg = W[r][:,0:256]@ctx[t] + W[r][:,256:320]@childval[t].
// ctx term + index metadata precomputed in k_ctx2 (relation-binned ACROSS
// layers -> real 64x64x256 register-tiled GEMM per block). ctxdot is stored
// in GLOBAL-SORT ORDER (g-order) so every k_ctx2 block writes one contiguous
// 16KB run (r3 lesson: scattered 256B-row stores cost 4-8x HBM write traffic:
// WRITE_SIZE 17.5MB pos-contig -> 148MB scattered). m_g[pos] maps back.
// Serial chain: ONE plain-launch kernel, hand-rolled monotonic grid barrier
// (no hipLaunchCooperativeKernel - r2's failure was its graph-capture path).
// All cross-layer data ops are coherence-point-direct (__hip_atomic relaxed
// agent = sc0 sc1, bypasses per-XCD L1/L2) so correctness does NOT depend on
// fence cache-flush semantics. Read-only data stays plain/cached.
// ---------------------------------------------------------------------------
constexpr size_t N_CHILD  = (size_t)BS_ * DEP_;              // 2,097,152 floats
constexpr size_t OFF_A0   = N_CHILD;                         // A0,A1,A2 follow
constexpr size_t OFF_WT   = N_CHILD * 4;
constexpr size_t N_WT     = (size_t)R_ * FEAT_ * DEP_;       // 1,024,000
constexpr size_t OFF_SORT = OFF_WT + N_WT;
constexpr size_t N_SORT   = (size_t)L_ * NEDGE_;             // 65,536 ints
constexpr size_t OFF_CHUNK= OFF_SORT + N_SORT;
constexpr size_t N_CHUNK_I= (size_t)L_ * NCH_ * 4;           // ints
constexpr size_t OFF_HC   = OFF_CHUNK + N_CHUNK_I;
constexpr size_t N_HC     = (size_t)L_ * BS_;                // 524,288 ints
constexpr size_t OFF_MT   = OFF_HC + N_HC;                   // m_trow (tch in sign)
constexpr size_t OFF_MH   = OFF_MT + N_SORT;                 // m_hrow
constexpr size_t OFF_MI   = OFF_MH + N_SORT;                 // m_invc
constexpr size_t OFF_CD   = OFF_MI + N_SORT;                 // ctxdot (g-order!)
constexpr size_t N_CD     = (size_t)L_ * NEDGE_ * DEP_;      // 4,194,304
constexpr size_t OFF_GIDX = OFF_CD + N_CD;                   // global bin: pos list
constexpr size_t OFF_GCH  = OFF_GIDX + N_SORT;               // int4 * NGC_
constexpr size_t OFF_HLR  = OFF_GCH + (size_t)NGC_ * 4;      // hist_lr [L*R] ints
constexpr size_t OFF_SLR  = OFF_HLR + (size_t)L_ * R_;       // start_lr [L*R] ints
constexpr size_t OFF_MG   = OFF_SLR + (size_t)L_ * R_;       // m_g: pos -> g
constexpr size_t OFF_BAR  = OFF_MG + N_SORT;                 // grid barrier

#define LD_SC(p)    __hip_atomic_load((p), __ATOMIC_RELAXED, __HIP_MEMORY_SCOPE_AGENT)
#define ST_SC(p, v) __hip_atomic_store((p), (v), __ATOMIC_RELAXED, __HIP_MEMORY_SCOPE_AGENT)

// ---------------------------------------------------------------------------
// K_PRE: blocks 0..15 = per-layer relation binning + chunk table + head-count
// hist (also publishes hist/start tables for k_gidx); blocks 16.. = W
// re-layout WT2[r][i4][k][c] + zero child+A0 + barrier counter.
// ---------------------------------------------------------------------------
__global__ void k_pre(const float* __restrict__ W, const int* __restrict__ rels,
                      const int* __restrict__ heads,
                      float* __restrict__ WT2, int* __restrict__ sorted,
                      int4* __restrict__ chunks, int* __restrict__ hc,
                      float* __restrict__ zero_base,
                      int* __restrict__ hist_lr, int* __restrict__ start_lr,
                      int* __restrict__ bar) {
  int blk = blockIdx.x, tid = threadIdx.x;
  if (blk < L_) {
    int l = blk;
    __shared__ int hist[R_], startA[R_], rank[R_], cstart[R_];
    __shared__ int ntot;
    if (tid < R_) { hist[tid] = 0; rank[tid] = 0; }
    int* hcl = hc + (size_t)l * BS_;
    for (int i = tid; i < BS_; i += 256) hcl[i] = 0;
    __syncthreads();
    for (int ed = tid; ed < NEDGE_; ed += 256) {
      int b = ed >> 7, e = ed & (E_ - 1);
      atomicAdd(&hist[rels[(b * L_ + l) * E_ + e]], 1);
      atomicAdd(&hcl[b * S_ + heads[(b * L_ + l) * E_ + e]], 1);
    }
    __syncthreads();
    if (tid == 0) {
      int s = 0, cs = 0;
      for (int r = 0; r < R_; ++r) {
        startA[r] = s; s += hist[r];
        cstart[r] = cs; cs += (hist[r] + CH_ - 1) / CH_;
      }
      ntot = cs;
    }
    __syncthreads();
    for (int ed = tid; ed < NEDGE_; ed += 256) {
      int b = ed >> 7, e = ed & (E_ - 1);
      int r = rels[(b * L_ + l) * E_ + e];
      int pos = startA[r] + atomicAdd(&rank[r], 1);
      sorted[l * NEDGE_ + pos] = ed;
    }
    if (tid < R_) {
      hist_lr[l * R_ + tid] = hist[tid];
      start_lr[l * R_ + tid] = startA[tid];
      int n = hist[tid], st = startA[tid], cs = cstart[tid];
      for (int m = 0; m * CH_ < n; ++m) {
        int c = n - m * CH_; if (c > CH_) c = CH_;
        chunks[l * NCH_ + cs + m] = make_int4(tid, st + m * CH_, c, 0);
      }
    }
    __syncthreads();
    for (int i = ntot + tid; i < NCH_; i += 256)
      chunks[l * NCH_ + i] = make_int4(0, 0, 0, 0);
  } else {
    int gtid = (blk - L_) * 256 + tid;
    if (gtid == 0) bar[0] = 0;
    const int NT = PREB_ * 256;
    for (int gid = gtid; gid < (int)N_WT; gid += NT) {
      int r = gid / 20480;           // 80*64*4
      int rem = gid - r * 20480;
      int i4 = rem >> 8;
      int k = (rem >> 2) & 63;
      int c = rem & 3;
      WT2[gid] = W[((size_t)r * DEP_ + k) * FEAT_ + 4 * i4 + c];
    }
    float4* z4 = (float4*)zero_base;          // child + A0, contiguous
    int nz4 = (int)((N_CHILD * 2) / 4);
    for (int i = gtid; i < nz4; i += NT) z4[i] = make_float4(0.f, 0.f, 0.f, 0.f);
  }
}

// ---------------------------------------------------------------------------
// K_GIDX: 800 blocks, one per (r,l) run. Each block redundantly computes the
// global r-grouped offsets from the published hist table and copies its run
// of `sorted` positions into gidx. Block 0 also emits the global chunk table.
// ---------------------------------------------------------------------------
__global__ void __launch_bounds__(256) k_gidx(
    const int* __restrict__ hist_lr, const int* __restrict__ start_lr,
    int* __restrict__ gidx, int4* __restrict__ gchunks) {
  int bid = blockIdx.x;           // bid = r*L_ + l
  int r = bid / L_, l = bid - r * L_;
  int tid = threadIdx.x;
  __shared__ int sh[L_ * R_];
  __shared__ int base_s, ntot_s;
  for (int i = tid; i < L_ * R_; i += 256) sh[i] = hist_lr[i];
  __syncthreads();
  if (tid == 0) {
    int goff = 0;
    for (int rr = 0; rr < r; ++rr)
      for (int ll = 0; ll < L_; ++ll) goff += sh[ll * R_ + rr];
    for (int ll = 0; ll < l; ++ll) goff += sh[ll * R_ + r];
    base_s = goff;
  }
  __syncthreads();
  int n = sh[l * R_ + r];
  int st = start_lr[l * R_ + r];
  int base = base_s;
  for (int i = tid; i < n; i += 256)
    gidx[base + i] = l * NEDGE_ + st + i;

  if (bid == 0) {
    __shared__ int tot[R_], goffA[R_], cstart[R_];
    if (tid < R_) {
      int t = 0;
      for (int ll = 0; ll < L_; ++ll) t += sh[ll * R_ + tid];
      tot[tid] = t;
    }
    __syncthreads();
    if (tid == 0) {
      int s = 0, cs = 0;
      for (int rr = 0; rr < R_; ++rr) {
        goffA[rr] = s; s += tot[rr];
        cstart[rr] = cs; cs += (tot[rr] + GCH_ - 1) / GCH_;
      }
      ntot_s = cs;
    }
    __syncthreads();
    if (tid < R_) {
      int nn = tot[tid], go = goffA[tid], cs = cstart[tid];
      for (int m = 0; m * GCH_ < nn; ++m) {
        int c = nn - m * GCH_; if (c > GCH_) c = GCH_;
        gchunks[cs + m] = make_int4(tid, go + m * GCH_, c, 0);
      }
    }
    __syncthreads();
    for (int i = ntot_s + tid; i < NGC_; i += 256)
      gchunks[i] = make_int4(0, 0, 0, 0);
  }
}

__device__ __forceinline__ float dot64(const float4* __restrict__ f4,
                                       const float4* __restrict__ w) {
  float a0 = 0.f, a1 = 0.f, a2 = 0.f, a3 = 0.f;
#pragma unroll
  for (int i = 0; i < 16; ++i) {
    float4 f = f4[i];
    a0 = fmaf(w[i].x, f.x, a0);
    a1 = fmaf(w[i].y, f.y, a1);
    a2 = fmaf(w[i].z, f.z, a2);
    a3 = fmaf(w[i].w, f.w, a3);
  }
  return (a0 + a1) + (a2 + a3);
}

__device__ __forceinline__ void fma4(float& a, float4 w, float4 f) {
  a = fmaf(w.x, f.x, a);
  a = fmaf(w.y, f.y, a);
  a = fmaf(w.z, f.z, a);
  a = fmaf(w.w, f.w, a);
}

// ---------------------------------------------------------------------------
// K_CTX2: register-tiled GEMM per global relation-chunk (64k x 64j x 256).
// Thread (tk,tj) computes 4x4 tile with k = tk+16a (conflict-free Wn_s reads,
// r3-verified: 13.3M -> 0.5M). Epilogue: LDS transpose (reusing Wn_s) then
// tid-linear float4 stores -> ONE contiguous 16KB ctxdot run per block
// (g-order). Writes m_g[pos] so the chain can find its rows.
// ---------------------------------------------------------------------------
__global__ void __launch_bounds__(256, 4) k_ctx2(
    const float* __restrict__ context, const float* __restrict__ WT2,
    const int* __restrict__ heads, const int* __restrict__ tails,
    const int* __restrict__ sorted, const int4* __restrict__ gchunks,
    const int* __restrict__ gidx, const int* __restrict__ hc,
    float* __restrict__ ctxdot, int* __restrict__ m_trow,
    int* __restrict__ m_hrow, float* __restrict__ m_invc,
    int* __restrict__ m_g) {
  int4 ck = gchunks[blockIdx.x];
  int r = ck.x, gstart = ck.y, gcnt = ck.z;
  if (gcnt == 0) return;
  int tid = threadIdx.x;
  int tk = tid & 15, tj = tid >> 4;

  __shared__ float4 Wn_s[16 * 64];                 // 16 KB, one 64-d panel of W
  __shared__ __align__(16) float F_s[GCH_][68];    // 17.4 KB gathered ctx panel
  __shared__ int   trow_s[GCH_];
  __shared__ float invc_s[GCH_];

  if (tid < GCH_) {
    int jj = (tid < gcnt) ? tid : (gcnt - 1);
    int pos = gidx[gstart + jj];
    int l = pos >> 12;                             // NEDGE_ = 4096
    int ed = sorted[pos];
    int b = ed >> 7, e = ed & (E_ - 1);
    int t = tails[(b * L_ + l) * E_ + e];
    int h = heads[(b * L_ + l) * E_ + e];
    int trow = b * S_ + t, hrow = b * S_ + h;
    float invc = 1.0f / (float)hc[(size_t)l * BS_ + hrow];   // >= 1
    trow_s[tid] = trow;
    invc_s[tid] = invc;
    if (tid < gcnt) {
      int tch = (l > 0) && (hc[(size_t)(l - 1) * BS_ + trow] > 0);
      m_trow[pos] = trow | (tch ? (int)0x80000000 : 0);
      m_hrow[pos] = hrow;
      m_invc[pos] = invc;
      m_g[pos] = gstart + tid;
    }
  }
  __syncthreads();

  float acc[4][4] = {};
  const float4* ctx4 = (const float4*)context;
  const float4* W4 = (const float4*)WT2 + (size_t)r * 80 * 64;

  int jrow = tid >> 2;        // F-staging: 4 threads per edge row
  int c0 = tid & 3;
  int trowj = trow_s[jrow];

  float4 wreg[4], freg[4];
#pragma unroll
  for (int rep = 0; rep < 4; ++rep) {
    wreg[rep] = W4[256 * rep + tid];
    freg[rep] = ctx4[(size_t)trowj * 64 + (c0 + 4 * rep)];
  }

  for (int dp = 0; dp < 4; ++dp) {
    // land staged regs into LDS
#pragma unroll
    for (int rep = 0; rep < 4; ++rep) {
      Wn_s[256 * rep + tid] = wreg[rep];
      *(float4*)&F_s[jrow][4 * (c0 + 4 * rep)] = freg[rep];
    }
    __syncthreads();

    if (dp < 3) {   // issue next panel's loads; hidden under the FMA phase
#pragma unroll
      for (int rep = 0; rep < 4; ++rep) {
        wreg[rep] = W4[1024 * (dp + 1) + 256 * rep + tid];
        freg[rep] = ctx4[(size_t)trowj * 64 + (dp + 1) * 16 + (c0 + 4 * rep)];
      }
    }

#pragma unroll
    for (int i4 = 0; i4 < 16; ++i4) {
      float4 wv[4], fv[4];
#pragma unroll
      for (int a = 0; a < 4; ++a) wv[a] = Wn_s[i4 * 64 + tk + 16 * a];
#pragma unroll
      for (int bb = 0; bb < 4; ++bb)
        fv[bb] = *(const float4*)&F_s[4 * tj + bb][4 * i4];
#pragma unroll
      for (int a = 0; a < 4; ++a)
#pragma unroll
        for (int bb = 0; bb < 4; ++bb) fma4(acc[a][bb], wv[a], fv[bb]);
    }
    __syncthreads();
  }

  // epilogue: scale by invc, transpose through LDS (Wn_s is free), then
  // tid-linear float4 stores -> one contiguous 16KB streaming write.
  float* Tr = (float*)Wn_s;                        // [64][64] j-major
#pragma unroll
  for (int bb = 0; bb < 4; ++bb) {
    int j = 4 * tj + bb;
    float iv = invc_s[j];
#pragma unroll
    for (int a = 0; a < 4; ++a) Tr[j * 64 + tk + 16 * a] = acc[a][bb] * iv;
  }
  __syncthreads();
  float4* dst = (float4*)(ctxdot + (size_t)gstart * DEP_);
  const float4* Tr4 = (const float4*)Tr;
  int n4 = gcnt * 16;
  for (int t = tid; t < n4; t += 256) dst[t] = Tr4[t];
}

// ---------------------------------------------------------------------------
// K_CHAIN: fused 16-layer serial chain + output assembly, ONE plain launch.
// Hand-rolled monotonic grid barrier between layers (320 blocks, guaranteed
// co-resident at launch_bounds(256,2): capacity >= 512). Every read of
// atomically/cross-block-written state uses LD_SC/ST_SC (relaxed agent =
// sc0 sc1, coherence-point-direct) -> correctness independent of fence
// cache-flush behavior. Read-only tables stay plain (L1/L2 cached).
// ---------------------------------------------------------------------------
__global__ void __launch_bounds__(256, 2) k_chain(
    const float* __restrict__ WT2, float* __restrict__ child,
    const int4* __restrict__ chunks, const int* __restrict__ m_trow,
    const int* __restrict__ m_hrow, const float* __restrict__ m_invc,
    const float* __restrict__ ctxdot, const int* __restrict__ m_g,
    float* __restrict__ A0, float* __restrict__ A1, float* __restrict__ A2,
    const float4* __restrict__ ctx4, const int* __restrict__ hc15,
    float4* __restrict__ out4, int* __restrict__ bar) {
  int tid = threadIdx.x;
  __shared__ float feat[CH_][DEP_];          // 4 KB
  float* Abuf[3] = {A0, A1, A2};

  for (int l = 0; l < L_; ++l) {
    float* Acur = Abuf[l % 3];
    float* Aprev = Abuf[(l + 2) % 3];
    float* Anext = Abuf[(l + 1) % 3];

    int4 ck = chunks[l * NCH_ + blockIdx.x];
    int r = ck.x, start = ck.y, ccnt = ck.z;

    if (ccnt > 0) {
      int wv = tid >> 6, k = tid & 63;

      // W child-slice register cache (i4 = 64..79); read-only -> plain
      const float4* Wp = (const float4*)WT2 + ((size_t)r * 80 + 64) * 64 + k;
      float4 w[16];
#pragma unroll
      for (int i = 0; i < 16; ++i) w[i] = Wp[(size_t)i * 64];

      int jj[4], valid[4], tch[4], trow[4], hrow[4], gg[4];
      float invc[4];
#pragma unroll
      for (int u = 0; u < 4; ++u) {
        int j = wv + 4 * u;
        valid[u] = (j < ccnt);
        jj[u] = valid[u] ? j : (ccnt - 1);
        int pos = l * NEDGE_ + start + jj[u];
        int tr = m_trow[pos];
        tch[u] = (tr < 0);
        trow[u] = tr & 0x7fffffff;
        hrow[u] = m_hrow[pos];
        invc[u] = m_invc[pos];
        gg[u] = m_g[pos];
      }

      float v[4];
#pragma unroll
      for (int u = 0; u < 4; ++u) {
        const float* p = tch[u] ? Aprev : child;   // A holds averages already
        v[u] = LD_SC(&p[(size_t)trow[u] * DEP_ + k]);
      }
#pragma unroll
      for (int u = 0; u < 4; ++u) feat[jj[u]][k] = v[u];
      __syncthreads();

#pragma unroll
      for (int u = 0; u < 4; ++u) {
        float d = dot64((const float4*)&feat[jj[u]][0], w);
        float contrib = d * invc[u] + ctxdot[(size_t)gg[u] * DEP_ + k];
        if (valid[u]) atomicAdd(&Acur[(size_t)hrow[u] * DEP_ + k], contrib);
      }
      __syncthreads();   // feat safe for next layer (also barrier below)
    }

    // Deferred row-disjoint phases (scalar, coherence-point-direct)
    int gtid = blockIdx.x * 256 + tid;
    const int NT = NCH_ * 256;
    if (l > 0) {
      const int* mh = m_hrow + (size_t)(l - 1) * NEDGE_;
      for (int idx = gtid; idx < NEDGE_ * DEP_; idx += NT) {
        int pos = idx >> 6, c = idx & 63;
        size_t off = (size_t)mh[pos] * DEP_ + c;
        ST_SC(&child[off], LD_SC(&Aprev[off]));
      }
    }
    if (l + 1 < L_) {
      const int* mh = m_hrow + (size_t)(l + 1) * NEDGE_;
      for (int idx = gtid; idx < NEDGE_ * DEP_; idx += NT) {
        int pos = idx >> 6, c = idx & 63;
        ST_SC(&Anext[(size_t)mh[pos] * DEP_ + c], 0.0f);
      }
    }

    // ---- grid barrier (monotonic counter; release on arrive, acquire spin)
    __syncthreads();
    if (tid == 0) {
      __hip_atomic_fetch_add(bar, 1, __ATOMIC_RELEASE, __HIP_MEMORY_SCOPE_AGENT);
      int target = (l + 1) * NCH_;
      while (__hip_atomic_load(bar, __ATOMIC_ACQUIRE, __HIP_MEMORY_SCOPE_AGENT) < target)
        __builtin_amdgcn_s_sleep(8);
    }
    __syncthreads();
  }

  // Output assembly: out = concat(context, childval); layer-15 rows from A0.
  constexpr int TOT4 = B_ * S_ * (FEAT_ / 4);
  for (int i = blockIdx.x * 256 + tid; i < TOT4; i += NCH_ * 256) {
    int row = i / 80;
    int c4 = i - row * 80;
    float4 v;
    if (c4 < 64) {
      v = ctx4[(size_t)row * 64 + c4];
    } else {
      int k4 = c4 - 64;
      const float* src = (hc15[row] > 0) ? A0 : child;
      size_t off = (size_t)row * DEP_ + 4 * k4;
      v.x = LD_SC(&src[off + 0]);
      v.y = LD_SC(&src[off + 1]);
      v.z = LD_SC(&src[off + 2]);
      v.w = LD_SC(&src[off + 3]);
    }
    out4[i] = v;
  }
}

extern "C" void kernel_launch(void* const* d_in, const int* in_sizes, int n_in,
                              void* d_out, int out_size, void* d_ws, size_t ws_size,
                              hipStream_t stream) {
  const float* context = (const float*)d_in[0];
  const float* dep_W   = (const float*)d_in[1];
  const int*   heads   = (const int*)d_in[2];
  const int*   tails   = (const int*)d_in[3];
  const int*   rels    = (const int*)d_in[4];
  float* out = (float*)d_out;

  float* ws = (float*)d_ws;
  float* child  = ws;
  float* A0 = ws + OFF_A0;
  float* A1 = ws + OFF_A0 + N_CHILD;
  float* A2 = ws + OFF_A0 + 2 * N_CHILD;
  float* WT2    = ws + OFF_WT;
  int*   sorted = (int*)(ws + OFF_SORT);
  int4*  chunks = (int4*)(ws + OFF_CHUNK);
  int*   hc     = (int*)(ws + OFF_HC);
  int*   m_trow = (int*)(ws + OFF_MT);
  int*   m_hrow = (int*)(ws + OFF_MH);
  float* m_invc = ws + OFF_MI;
  float* ctxdot = ws + OFF_CD;
  int*   gidx   = (int*)(ws + OFF_GIDX);
  int4*  gchunks= (int4*)(ws + OFF_GCH);
  int*   hist_lr= (int*)(ws + OFF_HLR);
  int*   start_lr=(int*)(ws + OFF_SLR);
  int*   m_g    = (int*)(ws + OFF_MG);
  int*   bar    = (int*)(ws + OFF_BAR);

  k_pre<<<L_ + PREB_, 256, 0, stream>>>(dep_W, rels, heads, WT2, sorted,
                                        chunks, hc, child, hist_lr, start_lr,
                                        bar);

  k_gidx<<<R_ * L_, 256, 0, stream>>>(hist_lr, start_lr, gidx, gchunks);

  k_ctx2<<<NGC_, 256, 0, stream>>>(context, WT2, heads, tails, sorted,
                                   gchunks, gidx, hc, ctxdot, m_trow, m_hrow,
                                   m_invc, m_g);

  k_chain<<<NCH_, 256, 0, stream>>>(WT2, child, chunks, m_trow, m_hrow,
                                    m_invc, ctxdot, m_g, A0, A1, A2,
                                    (const float4*)context,
                                    hc + (size_t)(L_ - 1) * BS_,
                                    (float4*)out, bar);
}

// Round 5
// 835.817 us; speedup vs baseline: 1.0414x; 1.0414x over previous
//
#include <hip/hip_runtime.h>

// Problem constants: B,S,NODE,DEP,R,L,E = 32,1024,256,64,50,16,128
constexpr int B_ = 32;
constexpr int S_ = 1024;
constexpr int NODE_ = 256;
constexpr int DEP_ = 64;
constexpr int R_ = 50;
constexpr int L_ = 16;
constexpr int E_ = 128;
constexpr int FEAT_ = NODE_ + DEP_;     // 320
constexpr int NEDGE_ = B_ * E_;         // 4096 edges per layer
constexpr int BS_ = B_ * S_;            // 32768 rows
constexpr int CH_ = 16;                 // edges per relation-chunk (chain)
constexpr int NCH_ = 320;               // sum ceil(n_r/16) <= 306
constexpr int PREB_ = 512;              // worker blocks in k_pre
constexpr int GCH_ = 64;                // edges per GLOBAL relation-chunk (k_ctx2)
constexpr int NGC_ = 1088;              // >= 50 + 65536/64 = 1074

// ---------------------------------------------------------------------------
// Key algebra: msg = W[r][:,0:256]@ctx[t] + W[r][:,256:320]@childval[t].
// ctx term + index metadata precomputed in k_ctx2 (relation-binned ACROSS
// layers -> real 64x64x256 register-tiled GEMM per block; ctxdot stored in
// g-order so each block writes one contiguous 16KB run).
// Serial chain: ONE plain-launch kernel. Proven-correct (r4) coherence rule:
// ALL cross-layer data goes through the coherence point (relaxed-agent
// __hip_atomic ops = sc0 sc1, bypass per-XCD L1/L2; atomicAdd is PoC-RMW);
// read-only tables stay plain/cached. r4's 680us was LATENCY, not coherence:
// (a) single-counter RMW barrier (320 serialized PoC RMWs + contended spin),
// (b) scalar 4B sc-ops. Fix: contention-free arrive[]/done flag barrier
// (release/acquire, monotonic l+1, no reset) + 8B sc-ops + k_out as its own
// kernel (kernel boundary = free coherence, full-grid parallel).
// ---------------------------------------------------------------------------
constexpr size_t N_CHILD  = (size_t)BS_ * DEP_;              // 2,097,152 floats
constexpr size_t OFF_A0   = N_CHILD;                         // A0,A1,A2 follow
constexpr size_t OFF_WT   = N_CHILD * 4;
constexpr size_t N_WT     = (size_t)R_ * FEAT_ * DEP_;       // 1,024,000
constexpr size_t OFF_SORT = OFF_WT + N_WT;
constexpr size_t N_SORT   = (size_t)L_ * NEDGE_;             // 65,536 ints
constexpr size_t OFF_CHUNK= OFF_SORT + N_SORT;
constexpr size_t N_CHUNK_I= (size_t)L_ * NCH_ * 4;           // ints
constexpr size_t OFF_HC   = OFF_CHUNK + N_CHUNK_I;
constexpr size_t N_HC     = (size_t)L_ * BS_;                // 524,288 ints
constexpr size_t OFF_MT   = OFF_HC + N_HC;                   // m_trow (tch in sign)
constexpr size_t OFF_MH   = OFF_MT + N_SORT;                 // m_hrow
constexpr size_t OFF_MI   = OFF_MH + N_SORT;                 // m_invc
constexpr size_t OFF_CD   = OFF_MI + N_SORT;                 // ctxdot (g-order!)
constexpr size_t N_CD     = (size_t)L_ * NEDGE_ * DEP_;      // 4,194,304
constexpr size_t OFF_GIDX = OFF_CD + N_CD;                   // global bin: pos list
constexpr size_t OFF_GCH  = OFF_GIDX + N_SORT;               // int4 * NGC_
constexpr size_t OFF_HLR  = OFF_GCH + (size_t)NGC_ * 4;      // hist_lr [L*R] ints
constexpr size_t OFF_SLR  = OFF_HLR + (size_t)L_ * R_;       // start_lr [L*R] ints
constexpr size_t OFF_MG   = OFF_SLR + (size_t)L_ * R_;       // m_g: pos -> g
constexpr size_t OFF_BAR  = OFF_MG + N_SORT;                 // done + arrive[NCH_]

typedef unsigned long long u64;
#define LD_SC(p)    __hip_atomic_load((p), __ATOMIC_RELAXED, __HIP_MEMORY_SCOPE_AGENT)
#define ST_SC(p, v) __hip_atomic_store((p), (v), __ATOMIC_RELAXED, __HIP_MEMORY_SCOPE_AGENT)

// ---------------------------------------------------------------------------
// K_PRE: blocks 0..15 = per-layer relation binning + chunk table + head-count
// hist (also publishes hist/start tables for k_gidx); blocks 16.. = W
// re-layout WT2[r][i4][k][c] + zero child+A0 + barrier flags.
// ---------------------------------------------------------------------------
__global__ void k_pre(const float* __restrict__ W, const int* __restrict__ rels,
                      const int* __restrict__ heads,
                      float* __restrict__ WT2, int* __restrict__ sorted,
                      int4* __restrict__ chunks, int* __restrict__ hc,
                      float* __restrict__ zero_base,
                      int* __restrict__ hist_lr, int* __restrict__ start_lr,
                      int* __restrict__ bar) {
  int blk = blockIdx.x, tid = threadIdx.x;
  if (blk < L_) {
    int l = blk;
    __shared__ int hist[R_], startA[R_], rank[R_], cstart[R_];
    __shared__ int ntot;
    if (tid < R_) { hist[tid] = 0; rank[tid] = 0; }
    int* hcl = hc + (size_t)l * BS_;
    for (int i = tid; i < BS_; i += 256) hcl[i] = 0;
    __syncthreads();
    for (int ed = tid; ed < NEDGE_; ed += 256) {
      int b = ed >> 7, e = ed & (E_ - 1);
      atomicAdd(&hist[rels[(b * L_ + l) * E_ + e]], 1);
      atomicAdd(&hcl[b * S_ + heads[(b * L_ + l) * E_ + e]], 1);
    }
    __syncthreads();
    if (tid == 0) {
      int s = 0, cs = 0;
      for (int r = 0; r < R_; ++r) {
        startA[r] = s; s += hist[r];
        cstart[r] = cs; cs += (hist[r] + CH_ - 1) / CH_;
      }
      ntot = cs;
    }
    __syncthreads();
    for (int ed = tid; ed < NEDGE_; ed += 256) {
      int b = ed >> 7, e = ed & (E_ - 1);
      int r = rels[(b * L_ + l) * E_ + e];
      int pos = startA[r] + atomicAdd(&rank[r], 1);
      sorted[l * NEDGE_ + pos] = ed;
    }
    if (tid < R_) {
      hist_lr[l * R_ + tid] = hist[tid];
      start_lr[l * R_ + tid] = startA[tid];
      int n = hist[tid], st = startA[tid], cs = cstart[tid];
      for (int m = 0; m * CH_ < n; ++m) {
        int c = n - m * CH_; if (c > CH_) c = CH_;
        chunks[l * NCH_ + cs + m] = make_int4(tid, st + m * CH_, c, 0);
      }
    }
    __syncthreads();
    for (int i = ntot + tid; i < NCH_; i += 256)
      chunks[l * NCH_ + i] = make_int4(0, 0, 0, 0);
  } else {
    int gtid = (blk - L_) * 256 + tid;
    const int NT = PREB_ * 256;
    for (int i = gtid; i < 1 + NCH_; i += NT) bar[i] = 0;   // done + arrive[]
    for (int gid = gtid; gid < (int)N_WT; gid += NT) {
      int r = gid / 20480;           // 80*64*4
      int rem = gid - r * 20480;
      int i4 = rem >> 8;
      int k = (rem >> 2) & 63;
      int c = rem & 3;
      WT2[gid] = W[((size_t)r * DEP_ + k) * FEAT_ + 4 * i4 + c];
    }
    float4* z4 = (float4*)zero_base;          // child + A0, contiguous
    int nz4 = (int)((N_CHILD * 2) / 4);
    for (int i = gtid; i < nz4; i += NT) z4[i] = make_float4(0.f, 0.f, 0.f, 0.f);
  }
}

// ---------------------------------------------------------------------------
// K_GIDX: 800 blocks, one per (r,l) run. Each block redundantly computes the
// global r-grouped offsets from the published hist table and copies its run
// of `sorted` positions into gidx. Block 0 also emits the global chunk table.
// ---------------------------------------------------------------------------
__global__ void __launch_bounds__(256) k_gidx(
    const int* __restrict__ hist_lr, const int* __restrict__ start_lr,
    int* __restrict__ gidx, int4* __restrict__ gchunks) {
  int bid = blockIdx.x;           // bid = r*L_ + l
  int r = bid / L_, l = bid - r * L_;
  int tid = threadIdx.x;
  __shared__ int sh[L_ * R_];
  __shared__ int base_s, ntot_s;
  for (int i = tid; i < L_ * R_; i += 256) sh[i] = hist_lr[i];
  __syncthreads();
  if (tid == 0) {
    int goff = 0;
    for (int rr = 0; rr < r; ++rr)
      for (int ll = 0; ll < L_; ++ll) goff += sh[ll * R_ + rr];
    for (int ll = 0; ll < l; ++ll) goff += sh[ll * R_ + r];
    base_s = goff;
  }
  __syncthreads();
  int n = sh[l * R_ + r];
  int st = start_lr[l * R_ + r];
  int base = base_s;
  for (int i = tid; i < n; i += 256)
    gidx[base + i] = l * NEDGE_ + st + i;

  if (bid == 0) {
    __shared__ int tot[R_], goffA[R_], cstart[R_];
    if (tid < R_) {
      int t = 0;
      for (int ll = 0; ll < L_; ++ll) t += sh[ll * R_ + tid];
      tot[tid] = t;
    }
    __syncthreads();
    if (tid == 0) {
      int s = 0, cs = 0;
      for (int rr = 0; rr < R_; ++rr) {
        goffA[rr] = s; s += tot[rr];
        cstart[rr] = cs; cs += (tot[rr] + GCH_ - 1) / GCH_;
      }
      ntot_s = cs;
    }
    __syncthreads();
    if (tid < R_) {
      int nn = tot[tid], go = goffA[tid], cs = cstart[tid];
      for (int m = 0; m * GCH_ < nn; ++m) {
        int c = nn - m * GCH_; if (c > GCH_) c = GCH_;
        gchunks[cs + m] = make_int4(tid, go + m * GCH_, c, 0);
      }
    }
    __syncthreads();
    for (int i = ntot_s + tid; i < NGC_; i += 256)
      gchunks[i] = make_int4(0, 0, 0, 0);
  }
}

__device__ __forceinline__ float dot64(const float4* __restrict__ f4,
                                       const float4* __restrict__ w) {
  float a0 = 0.f, a1 = 0.f, a2 = 0.f, a3 = 0.f;
#pragma unroll
  for (int i = 0; i < 16; ++i) {
    float4 f = f4[i];
    a0 = fmaf(w[i].x, f.x, a0);
    a1 = fmaf(w[i].y, f.y, a1);
    a2 = fmaf(w[i].z, f.z, a2);
    a3 = fmaf(w[i].w, f.w, a3);
  }
  return (a0 + a1) + (a2 + a3);
}

__device__ __forceinline__ void fma4(float& a, float4 w, float4 f) {
  a = fmaf(w.x, f.x, a);
  a = fmaf(w.y, f.y, a);
  a = fmaf(w.z, f.z, a);
  a = fmaf(w.w, f.w, a);
}

// ---------------------------------------------------------------------------
// K_CTX2: register-tiled GEMM per global relation-chunk (64k x 64j x 256).
// Thread (tk,tj) computes 4x4 tile with k = tk+16a (conflict-free Wn_s reads).
// Epilogue: LDS transpose (reusing Wn_s) then tid-linear float4 stores ->
// ONE contiguous 16KB ctxdot run per block (g-order). Writes m_g[pos].
// ---------------------------------------------------------------------------
__global__ void __launch_bounds__(256, 4) k_ctx2(
    const float* __restrict__ context, const float* __restrict__ WT2,
    const int* __restrict__ heads, const int* __restrict__ tails,
    const int* __restrict__ sorted, const int4* __restrict__ gchunks,
    const int* __restrict__ gidx, const int* __restrict__ hc,
    float* __restrict__ ctxdot, int* __restrict__ m_trow,
    int* __restrict__ m_hrow, float* __restrict__ m_invc,
    int* __restrict__ m_g) {
  int4 ck = gchunks[blockIdx.x];
  int r = ck.x, gstart = ck.y, gcnt = ck.z;
  if (gcnt == 0) return;
  int tid = threadIdx.x;
  int tk = tid & 15, tj = tid >> 4;

  __shared__ float4 Wn_s[16 * 64];                 // 16 KB, one 64-d panel of W
  __shared__ __align__(16) float F_s[GCH_][68];    // 17.4 KB gathered ctx panel
  __shared__ int   trow_s[GCH_];
  __shared__ float invc_s[GCH_];

  if (tid < GCH_) {
    int jj = (tid < gcnt) ? tid : (gcnt - 1);
    int pos = gidx[gstart + jj];
    int l = pos >> 12;                             // NEDGE_ = 4096
    int ed = sorted[pos];
    int b = ed >> 7, e = ed & (E_ - 1);
    int t = tails[(b * L_ + l) * E_ + e];
    int h = heads[(b * L_ + l) * E_ + e];
    int trow = b * S_ + t, hrow = b * S_ + h;
    float invc = 1.0f / (float)hc[(size_t)l * BS_ + hrow];   // >= 1
    trow_s[tid] = trow;
    invc_s[tid] = invc;
    if (tid < gcnt) {
      int tch = (l > 0) && (hc[(size_t)(l - 1) * BS_ + trow] > 0);
      m_trow[pos] = trow | (tch ? (int)0x80000000 : 0);
      m_hrow[pos] = hrow;
      m_invc[pos] = invc;
      m_g[pos] = gstart + tid;
    }
  }
  __syncthreads();

  float acc[4][4] = {};
  const float4* ctx4 = (const float4*)context;
  const float4* W4 = (const float4*)WT2 + (size_t)r * 80 * 64;

  int jrow = tid >> 2;        // F-staging: 4 threads per edge row
  int c0 = tid & 3;
  int trowj = trow_s[jrow];

  float4 wreg[4], freg[4];
#pragma unroll
  for (int rep = 0; rep < 4; ++rep) {
    wreg[rep] = W4[256 * rep + tid];
    freg[rep] = ctx4[(size_t)trowj * 64 + (c0 + 4 * rep)];
  }

  for (int dp = 0; dp < 4; ++dp) {
    // land staged regs into LDS
#pragma unroll
    for (int rep = 0; rep < 4; ++rep) {
      Wn_s[256 * rep + tid] = wreg[rep];
      *(float4*)&F_s[jrow][4 * (c0 + 4 * rep)] = freg[rep];
    }
    __syncthreads();

    if (dp < 3) {   // issue next panel's loads; hidden under the FMA phase
#pragma unroll
      for (int rep = 0; rep < 4; ++rep) {
        wreg[rep] = W4[1024 * (dp + 1) + 256 * rep + tid];
        freg[rep] = ctx4[(size_t)trowj * 64 + (dp + 1) * 16 + (c0 + 4 * rep)];
      }
    }

#pragma unroll
    for (int i4 = 0; i4 < 16; ++i4) {
      float4 wv[4], fv[4];
#pragma unroll
      for (int a = 0; a < 4; ++a) wv[a] = Wn_s[i4 * 64 + tk + 16 * a];
#pragma unroll
      for (int bb = 0; bb < 4; ++bb)
        fv[bb] = *(const float4*)&F_s[4 * tj + bb][4 * i4];
#pragma unroll
      for (int a = 0; a < 4; ++a)
#pragma unroll
        for (int bb = 0; bb < 4; ++bb) fma4(acc[a][bb], wv[a], fv[bb]);
    }
    __syncthreads();
  }

  // epilogue: scale by invc, transpose through LDS (Wn_s is free), then
  // tid-linear float4 stores -> one contiguous 16KB streaming write.
  float* Tr = (float*)Wn_s;                        // [64][64] j-major
#pragma unroll
  for (int bb = 0; bb < 4; ++bb) {
    int j = 4 * tj + bb;
    float iv = invc_s[j];
#pragma unroll
    for (int a = 0; a < 4; ++a) Tr[j * 64 + tk + 16 * a] = acc[a][bb] * iv;
  }
  __syncthreads();
  float4* dst = (float4*)(ctxdot + (size_t)gstart * DEP_);
  const float4* Tr4 = (const float4*)Tr;
  int n4 = gcnt * 16;
  for (int t = tid; t < n4; t += 256) dst[t] = Tr4[t];
}

// ---------------------------------------------------------------------------
// K_CHAIN: fused 16-layer serial chain, ONE plain launch (320 blocks, coresi-
// dent at launch_bounds(256,2)). Coherence: all cross-layer data PoC-direct
// (LD_SC/ST_SC/atomicAdd) - r4-proven. Barrier v2 (contention-free):
//   arrive[b] = l+1 (release store, 320 distinct lines, parallel)
//   block0: 256 threads poll all 320 flags -> done = l+1 (release)
//   others: spin acquire on done. Monotonic l+1 -> no reset needed.
// __syncthreads() before arrival drains ALL waves' vm ops (compiler emits
// s_waitcnt vmcnt(0) before s_barrier) -> atomics complete before signal.
// ---------------------------------------------------------------------------
__global__ void __launch_bounds__(256, 2) k_chain(
    const float* __restrict__ WT2, float* __restrict__ child,
    const int4* __restrict__ chunks, const int* __restrict__ m_trow,
    const int* __restrict__ m_hrow, const float* __restrict__ m_invc,
    const float* __restrict__ ctxdot, const int* __restrict__ m_g,
    float* __restrict__ A0, float* __restrict__ A1, float* __restrict__ A2,
    int* __restrict__ bar) {
  int tid = threadIdx.x;
  __shared__ float feat[CH_][DEP_];          // 4 KB
  float* Abuf[3] = {A0, A1, A2};
  int* done = bar;
  int* arrive = bar + 1;

  for (int l = 0; l < L_; ++l) {
    float* Acur = Abuf[l % 3];
    const float* Aprev = Abuf[(l + 2) % 3];
    float* Anext = Abuf[(l + 1) % 3];

    int4 ck = chunks[l * NCH_ + blockIdx.x];
    int r = ck.x, start = ck.y, ccnt = ck.z;

    if (ccnt > 0) {
      int wv = tid >> 6, k = tid & 63;

      // W child-slice register cache (i4 = 64..79); read-only -> plain
      const float4* Wp = (const float4*)WT2 + ((size_t)r * 80 + 64) * 64 + k;
      float4 w[16];
#pragma unroll
      for (int i = 0; i < 16; ++i) w[i] = Wp[(size_t)i * 64];

      int jj[4], valid[4], tch[4], trow[4], hrow[4], gg[4];
      float invc[4];
#pragma unroll
      for (int u = 0; u < 4; ++u) {
        int j = wv + 4 * u;
        valid[u] = (j < ccnt);
        jj[u] = valid[u] ? j : (ccnt - 1);
        int pos = l * NEDGE_ + start + jj[u];
        int tr = m_trow[pos];
        tch[u] = (tr < 0);
        trow[u] = tr & 0x7fffffff;
        hrow[u] = m_hrow[pos];
        invc[u] = m_invc[pos];
        gg[u] = m_g[pos];
      }

      float v[4];
#pragma unroll
      for (int u = 0; u < 4; ++u) {
        const float* p = tch[u] ? Aprev : child;   // A holds averages already
        v[u] = LD_SC(&p[(size_t)trow[u] * DEP_ + k]);
      }
#pragma unroll
      for (int u = 0; u < 4; ++u) feat[jj[u]][k] = v[u];
      __syncthreads();

#pragma unroll
      for (int u = 0; u < 4; ++u) {
        float d = dot64((const float4*)&feat[jj[u]][0], w);
        float contrib = d * invc[u] + ctxdot[(size_t)gg[u] * DEP_ + k];
        if (valid[u]) atomicAdd(&Acur[(size_t)hrow[u] * DEP_ + k], contrib);
      }
    }

    // Deferred row-disjoint phases, 8B PoC-direct ops (row = 32 u64)
    int gtid = blockIdx.x * 256 + tid;
    const int NT = NCH_ * 256;
    if (l > 0) {
      const int* mh = m_hrow + (size_t)(l - 1) * NEDGE_;
      const u64* Ap8 = (const u64*)Aprev;
      u64* ch8 = (u64*)child;
      for (int idx = gtid; idx < NEDGE_ * 32; idx += NT) {
        int pos = idx >> 5, c2 = idx & 31;
        size_t off = (size_t)mh[pos] * 32 + c2;
        ST_SC(&ch8[off], LD_SC(&Ap8[off]));
      }
    }
    if (l + 1 < L_) {
      const int* mh = m_hrow + (size_t)(l + 1) * NEDGE_;
      u64* An8 = (u64*)Anext;
      for (int idx = gtid; idx < NEDGE_ * 32; idx += NT) {
        int pos = idx >> 5, c2 = idx & 31;
        ST_SC(&An8[(size_t)mh[pos] * 32 + c2], 0ull);
      }
    }

    // ---- grid barrier v2 (skip after last layer; kernel end covers k_out)
    if (l == L_ - 1) break;
    __syncthreads();   // drains vmcnt for ALL waves -> safe to signal
    if (tid == 0)
      __hip_atomic_store(&arrive[blockIdx.x], l + 1, __ATOMIC_RELEASE,
                         __HIP_MEMORY_SCOPE_AGENT);
    if (blockIdx.x == 0) {
      for (int slot = tid; slot < NCH_; slot += 256)
        while (__hip_atomic_load(&arrive[slot], __ATOMIC_ACQUIRE,
                                 __HIP_MEMORY_SCOPE_AGENT) < l + 1)
          __builtin_amdgcn_s_sleep(1);
      __syncthreads();
      if (tid == 0)
        __hip_atomic_store(done, l + 1, __ATOMIC_RELEASE,
                           __HIP_MEMORY_SCOPE_AGENT);
    } else {
      if (tid == 0)
        while (__hip_atomic_load(done, __ATOMIC_ACQUIRE,
                                 __HIP_MEMORY_SCOPE_AGENT) < l + 1)
          __builtin_amdgcn_s_sleep(1);
    }
    __syncthreads();
  }
}

// ---------------------------------------------------------------------------
// K_O: out = concat(context, childval); layer-15 rows read from A0 (averages).
// Separate launch: kernel boundary gives free coherence + full-grid reads.
// ---------------------------------------------------------------------------
__global__ void k_out(const float4* __restrict__ ctx4,
                      const float4* __restrict__ chd4,
                      const float4* __restrict__ A04,
                      const int* __restrict__ hc15,
                      float4* __restrict__ out4) {
  constexpr int TOT4 = B_ * S_ * (FEAT_ / 4);
  int i = blockIdx.x * blockDim.x + threadIdx.x;
  if (i >= TOT4) return;
  int row = i / 80;
  int c4 = i - row * 80;
  float4 v;
  if (c4 < 64) {
    v = ctx4[(size_t)row * 64 + c4];
  } else {
    int k4 = c4 - 64;
    v = (hc15[row] > 0) ? A04[(size_t)row * 16 + k4]
                        : chd4[(size_t)row * 16 + k4];
  }
  out4[i] = v;
}

extern "C" void kernel_launch(void* const* d_in, const int* in_sizes, int n_in,
                              void* d_out, int out_size, void* d_ws, size_t ws_size,
                              hipStream_t stream) {
  const float* context = (const float*)d_in[0];
  const float* dep_W   = (const float*)d_in[1];
  const int*   heads   = (const int*)d_in[2];
  const int*   tails   = (const int*)d_in[3];
  const int*   rels    = (const int*)d_in[4];
  float* out = (float*)d_out;

  float* ws = (float*)d_ws;
  float* child  = ws;
  float* A0 = ws + OFF_A0;
  float* A1 = ws + OFF_A0 + N_CHILD;
  float* A2 = ws + OFF_A0 + 2 * N_CHILD;
  float* WT2    = ws + OFF_WT;
  int*   sorted = (int*)(ws + OFF_SORT);
  int4*  chunks = (int4*)(ws + OFF_CHUNK);
  int*   hc     = (int*)(ws + OFF_HC);
  int*   m_trow = (int*)(ws + OFF_MT);
  int*   m_hrow = (int*)(ws + OFF_MH);
  float* m_invc = ws + OFF_MI;
  float* ctxdot = ws + OFF_CD;
  int*   gidx   = (int*)(ws + OFF_GIDX);
  int4*  gchunks= (int4*)(ws + OFF_GCH);
  int*   hist_lr= (int*)(ws + OFF_HLR);
  int*   start_lr=(int*)(ws + OFF_SLR);
  int*   m_g    = (int*)(ws + OFF_MG);
  int*   bar    = (int*)(ws + OFF_BAR);

  k_pre<<<L_ + PREB_, 256, 0, stream>>>(dep_W, rels, heads, WT2, sorted,
                                        chunks, hc, child, hist_lr, start_lr,
                                        bar);

  k_gidx<<<R_ * L_, 256, 0, stream>>>(hist_lr, start_lr, gidx, gchunks);

  k_ctx2<<<NGC_, 256, 0, stream>>>(context, WT2, heads, tails, sorted,
                                   gchunks, gidx, hc, ctxdot, m_trow, m_hrow,
                                   m_invc, m_g);

  k_chain<<<NCH_, 256, 0, stream>>>(WT2, child, chunks, m_trow, m_hrow,
                                    m_invc, ctxdot, m_g, A0, A1, A2, bar);

  constexpr int TOT4 = B_ * S_ * (FEAT_ / 4);
  k_out<<<(TOT4 + 255) / 256, 256, 0, stream>>>(
      (const float4*)context, (const float4*)child, (const float4*)A0,
      hc + (size_t)(L_ - 1) * BS_, (float4*)out);
}